// Round 12
// baseline (148.515 us; speedup 1.0000x reference)
//
#include <hip/hip_runtime.h>

// ConvAttention2d: B=4, DIM=384, HEADS=8, DH=64, INNER=512, H=W=56, KS=3
// fp32 in/out. bf16 MFMA GEMMs (fp32 accum), blocked bf16 buffers.
// R12: k/v stored d-contiguous (kT/vT[b][h][s][64]) -> natt reads LDS as
// b32 d-pairs with 33-dword row stride (conflict-free, halves LDS instrs);
// gemm1 k/v epilogue 8B stores; cvts merged; gemm3 128-s tile.

#define HW 3136
#define WIMG 56
#define SCALE 0.125f
#define NROW 33   // natt LDS row stride in dwords (33%32==1 -> conflict-free)

typedef __bf16 bf16x8_t __attribute__((ext_vector_type(8)));
typedef float f32x4_t __attribute__((ext_vector_type(4)));

__device__ __forceinline__ float bf2f(unsigned short u) {
    return __uint_as_float(((unsigned int)u) << 16);
}
__device__ __forceinline__ float blo(unsigned int c) { return __uint_as_float(c << 16); }
__device__ __forceinline__ float bhi(unsigned int c) { return __uint_as_float(c & 0xFFFF0000u); }
__device__ __forceinline__ unsigned short f2bf(float f) {
    unsigned int u = __float_as_uint(f);
    u += 0x7FFFu + ((u >> 16) & 1u);   // round-to-nearest-even
    return (unsigned short)(u >> 16);
}

// ---------------------------------------------------------------------------
// Merged conversion kernel. Blocks [0,2400): x transpose -> blocked xT
// [b][sblk25][kb12][128s][32k] (s padded to 3200, tail zeroed).
// Blocks [2400,2784): weights -> wT[12][12][128][32], wT3[3][16][128][32].
// ---------------------------------------------------------------------------
__global__ __launch_bounds__(256) void cvt_all(
    const float* __restrict__ x, const float* __restrict__ Wq,
    const float* __restrict__ Wkv, const float* __restrict__ Wo,
    unsigned short* __restrict__ xT, unsigned short* __restrict__ wT,
    unsigned short* __restrict__ wT3)
{
    __shared__ unsigned short Tl[64 * 36];
    const int bid = blockIdx.x;
    const int t = threadIdx.x;

    if (bid < 2400) {
        const int sblk = bid % 50, kblk = (bid / 50) % 12, b = bid / 600;
        if (sblk == 49) {               // zero-fill s in [3136,3200)
            unsigned short* dst = xT + (((size_t)b * 25 + 24) * 12 + kblk) * 4096 + 2048;
            *reinterpret_cast<uint4*>(dst + t * 8) = (uint4){0, 0, 0, 0};
            return;
        }
        const float* xp = x + ((size_t)b * 384 + (size_t)kblk * 32) * HW + sblk * 64;
        const int c = t >> 3;
#pragma unroll
        for (int i = 0; i < 2; i++) {
            const int sc = (t & 7) + 8 * i;
            const float4 v = *reinterpret_cast<const float4*>(xp + (size_t)c * HW + sc * 4);
            const int s4 = sc * 4;
            Tl[(s4 + 0) * 36 + c] = f2bf(v.x);
            Tl[(s4 + 1) * 36 + c] = f2bf(v.y);
            Tl[(s4 + 2) * 36 + c] = f2bf(v.z);
            Tl[(s4 + 3) * 36 + c] = f2bf(v.w);
        }
        __syncthreads();
        const int row = t >> 2, gran = t & 3;
        const uint2 lo = *reinterpret_cast<const uint2*>(&Tl[row * 36 + gran * 8]);
        const uint2 hi = *reinterpret_cast<const uint2*>(&Tl[row * 36 + gran * 8 + 4]);
        uint4 o; o.x = lo.x; o.y = lo.y; o.z = hi.x; o.w = hi.y;
        unsigned short* dst = xT + (((size_t)b * 25 + (sblk >> 1)) * 12 + kblk) * 4096
                            + (sblk & 1) * 2048;
        *reinterpret_cast<uint4*>(dst + t * 8) = o;
        return;
    }

    const int i = (bid - 2400) * 256 + t;    // [0, 98304)
    if (i < 73728) {                         // wT
        const int g = i & 3;
        const int idx3 = i >> 2;
        const int o128 = idx3 & 127;
        const int rest = idx3 >> 7;
        const int kb = rest % 12, oblk = rest / 12;
        const int o = oblk * 128 + o128;
        const int k0 = kb * 32 + g * 8;
        const float* src = (o < 512) ? (Wq + (size_t)o * 384 + k0)
                                     : (Wkv + (size_t)(o - 512) * 384 + k0);
        const float4 v0 = *reinterpret_cast<const float4*>(src);
        const float4 v1 = *reinterpret_cast<const float4*>(src + 4);
        uint4 u;
        u.x = (unsigned int)f2bf(v0.x) | ((unsigned int)f2bf(v0.y) << 16);
        u.y = (unsigned int)f2bf(v0.z) | ((unsigned int)f2bf(v0.w) << 16);
        u.z = (unsigned int)f2bf(v1.x) | ((unsigned int)f2bf(v1.y) << 16);
        u.w = (unsigned int)f2bf(v1.z) | ((unsigned int)f2bf(v1.w) << 16);
        reinterpret_cast<uint4*>(wT)[i] = u;
    } else {                                 // wT3
        const int j = i - 73728;             // [0, 24576)
        const int g = j & 3;
        const int idx3 = j >> 2;
        const int o128 = idx3 & 127;
        const int rest = idx3 >> 7;
        const int kb = rest % 16, oblk = rest / 16;
        const int o = oblk * 128 + o128;
        const float* src = Wo + (size_t)o * 512 + kb * 32 + g * 8;
        const float4 v0 = *reinterpret_cast<const float4*>(src);
        const float4 v1 = *reinterpret_cast<const float4*>(src + 4);
        uint4 u;
        u.x = (unsigned int)f2bf(v0.x) | ((unsigned int)f2bf(v0.y) << 16);
        u.y = (unsigned int)f2bf(v0.z) | ((unsigned int)f2bf(v0.w) << 16);
        u.z = (unsigned int)f2bf(v1.x) | ((unsigned int)f2bf(v1.y) << 16);
        u.w = (unsigned int)f2bf(v1.z) | ((unsigned int)f2bf(v1.w) << 16);
        reinterpret_cast<uint4*>(wT3)[j] = u;
    }
}

// ---------------------------------------------------------------------------
// GEMM1: 128o x 128s tile, BK=32, identity uint4 staging, 16 MFMA/wave/step.
// Epilogue: o<512 -> q (ch,s) layout; o>=512 -> kT/vT[b][h][s][64d]
// (d-contiguous, uint2 stores). grid (25, 12, 4).
// ---------------------------------------------------------------------------
__global__ __launch_bounds__(256) void gemm1(
    const unsigned short* __restrict__ xT,   // [b][25][12][128][32]
    const unsigned short* __restrict__ wT,   // [12][12][128][32]
    unsigned short* __restrict__ qb,         // (4,512,3136)
    unsigned short* __restrict__ kT,         // (4,8,3136,64)
    unsigned short* __restrict__ vT)         // (4,8,3136,64)
{
    __shared__ __align__(16) unsigned short A_lds[128 * 32];
    __shared__ __align__(16) unsigned short B_lds[128 * 32];

    const int sblk = blockIdx.x;
    const int oblk = blockIdx.y;
    const int b  = blockIdx.z;
    const int t  = threadIdx.x;
    const int lane = t & 63, w = t >> 6;
    const int quad = lane >> 4, mrow = lane & 15;
    const int wm = w >> 1, wn = w & 1;

    const unsigned short* wsrc = wT + ((size_t)oblk * 12) * 4096;
    const unsigned short* xsrc = xT + (((size_t)b * 25 + sblk) * 12) * 4096;

    f32x4_t acc[4][4];
#pragma unroll
    for (int m = 0; m < 4; m++)
#pragma unroll
        for (int n = 0; n < 4; n++) acc[m][n] = (f32x4_t){0.f, 0.f, 0.f, 0.f};

    for (int kb = 0; kb < 12; kb++) {
        const uint4 a0 = *reinterpret_cast<const uint4*>(wsrc + (size_t)kb * 4096 + t * 8);
        const uint4 a1 = *reinterpret_cast<const uint4*>(wsrc + (size_t)kb * 4096 + 2048 + t * 8);
        const uint4 b0 = *reinterpret_cast<const uint4*>(xsrc + (size_t)kb * 4096 + t * 8);
        const uint4 b1 = *reinterpret_cast<const uint4*>(xsrc + (size_t)kb * 4096 + 2048 + t * 8);

        __syncthreads();
        *reinterpret_cast<uint4*>(A_lds + t * 8) = a0;
        *reinterpret_cast<uint4*>(A_lds + 2048 + t * 8) = a1;
        *reinterpret_cast<uint4*>(B_lds + t * 8) = b0;
        *reinterpret_cast<uint4*>(B_lds + 2048 + t * 8) = b1;
        __syncthreads();

        bf16x8_t af[4], bf[4];
#pragma unroll
        for (int m = 0; m < 4; m++)
            af[m] = *reinterpret_cast<const bf16x8_t*>(&A_lds[(wm * 64 + m * 16 + mrow) * 32 + quad * 8]);
#pragma unroll
        for (int n = 0; n < 4; n++)
            bf[n] = *reinterpret_cast<const bf16x8_t*>(&B_lds[(wn * 64 + n * 16 + mrow) * 32 + quad * 8]);
#pragma unroll
        for (int m = 0; m < 4; m++)
#pragma unroll
            for (int n = 0; n < 4; n++)
                acc[m][n] = __builtin_amdgcn_mfma_f32_16x16x32_bf16(af[m], bf[n], acc[m][n], 0, 0, 0);
    }

    const int o0 = oblk * 128 + wm * 64;     // wave's 64-o base
    const int s0 = sblk * 128 + wn * 64;
    if (o0 < 512) {                          // q epilogue (ch,s)
        unsigned short* outb = qb + (size_t)b * 512 * HW;
#pragma unroll
        for (int m = 0; m < 4; m++)
#pragma unroll
            for (int n = 0; n < 4; n++) {
                const int ss = s0 + n * 16 + mrow;
                if (ss < HW) {
#pragma unroll
                    for (int r = 0; r < 4; r++)
                        outb[(size_t)(o0 + m * 16 + quad * 4 + r) * HW + ss] = f2bf(acc[m][n][r]);
                }
            }
    } else {                                 // k/v epilogue, d-contiguous
        const int rel = o0 - 512;            // [0,1024), mult of 64
        unsigned short* base = (rel < 512) ? kT : vT;
        const int h = (rel & 511) >> 6;
        unsigned short* hb = base + (size_t)(b * 8 + h) * HW * 64;
#pragma unroll
        for (int m = 0; m < 4; m++) {
            const int d0 = m * 16 + quad * 4;
#pragma unroll
            for (int n = 0; n < 4; n++) {
                const int ss = s0 + n * 16 + mrow;
                if (ss < HW) {
                    uint2 u;
                    u.x = (unsigned int)f2bf(acc[m][n][0]) | ((unsigned int)f2bf(acc[m][n][1]) << 16);
                    u.y = (unsigned int)f2bf(acc[m][n][2]) | ((unsigned int)f2bf(acc[m][n][3]) << 16);
                    *reinterpret_cast<uint2*>(hb + (size_t)ss * 64 + d0) = u;
                }
            }
        }
    }
}

// ---------------------------------------------------------------------------
// Neighborhood attention v4: K/V staged from kT/vT into LDS rows [192 s] x
// [64 d], row stride NROW=33 dwords (conflict-free per-lane-row b32 reads).
// Thread (w,lane): s = s0+lane, d-pairs p = w*8..w*8+7. Dots d-pair reads
// halve LDS instr count vs u16. Output: blocked aoT (2 uint4 stores).
// ---------------------------------------------------------------------------
__global__ __launch_bounds__(256) void natt4(
    const unsigned short* __restrict__ qb,   // (4,512,3136)
    const unsigned short* __restrict__ kT,   // (4,8,3136,64)
    const unsigned short* __restrict__ vT,   // (4,8,3136,64)
    unsigned short* __restrict__ aoT)        // [4][49][16][64][32]
{
    __shared__ __align__(16) unsigned int KV[2 * 192 * NROW];  // Kl | Vl
    unsigned int* Kl = KV;
    unsigned int* Vl = KV + 192 * NROW;
    float* dred = reinterpret_cast<float*>(KV);  // overlays Kl after dots

    const int t = threadIdx.x, lane = t & 63, w = t >> 6;
    const int sblk = blockIdx.x;
    const int s0 = sblk * 64;
    const int s  = s0 + lane;
    const int h  = blockIdx.y, b = blockIdx.z;
    const int y  = s / WIMG, xx = s % WIMG;

    const unsigned short* kg = kT + (size_t)(b * 8 + h) * HW * 64;
    const unsigned short* vg = vT + (size_t)(b * 8 + h) * HW * 64;

    // Stage K/V halo rows [s0-64, s0+128): 192 rows x 8 uint4 chunks each.
#pragma unroll
    for (int i = 0; i < 6; i++) {
        const int f = i * 256 + t;           // 0..1535
        const int row = f >> 3, col4 = f & 7;
        const int sg = min(max(s0 - 64 + row, 0), HW - 1);  // clamped rows only
        const uint4 k4 = *reinterpret_cast<const uint4*>(kg + (size_t)sg * 64 + col4 * 8);
        const uint4 v4 = *reinterpret_cast<const uint4*>(vg + (size_t)sg * 64 + col4 * 8);
        const int db = row * NROW + col4 * 4;
        Kl[db] = k4.x; Kl[db + 1] = k4.y; Kl[db + 2] = k4.z; Kl[db + 3] = k4.w;
        Vl[db] = v4.x; Vl[db + 1] = v4.y; Vl[db + 2] = v4.z; Vl[db + 3] = v4.w;
    }

    int   off33[9];
    float msk[9];
#pragma unroll
    for (int ty = 0; ty < 3; ty++)
#pragma unroll
        for (int tx = 0; tx < 3; tx++) {
            const int tap = ty * 3 + tx;
            const int ny = y + ty - 1, nx = xx + tx - 1;
            const bool v = (ny >= 0) && (ny < WIMG) && (nx >= 0) && (nx < WIMG);
            off33[tap] = (v ? ((ty - 1) * WIMG + (tx - 1)) : 0) * NROW;
            msk[tap]  = v ? 1.f : 0.f;
        }

    __syncthreads();

    // Dots: per d-pair p, one b32 read per tap (lane-distinct rows, stride 33
    // dwords -> conflict-free). q scalar (coalesced over lanes).
    const unsigned short* qp = qb + (size_t)b * 512 * HW + (size_t)(h * 64) * HW + s;
    const int rb0 = (lane + 64) * NROW;
    float dots[9];
#pragma unroll
    for (int tp = 0; tp < 9; tp++) dots[tp] = 0.f;
#pragma unroll 4
    for (int j = 0; j < 8; j++) {
        const int p = w * 8 + j;
        const float q0 = bf2f(qp[(size_t)(2 * p) * HW]);
        const float q1 = bf2f(qp[(size_t)(2 * p + 1) * HW]);
        const int rb = rb0 + p;
#pragma unroll
        for (int tp = 0; tp < 9; tp++) {
            const unsigned int c = Kl[rb + off33[tp]];
            dots[tp] += q0 * blo(c);
            dots[tp] += q1 * bhi(c);
        }
    }

    __syncthreads();   // all waves done reading Kl -> overlay dred
#pragma unroll
    for (int tp = 0; tp < 9; tp++) dred[(tp * 4 + w) * 64 + lane] = dots[tp];
    __syncthreads();

    float mx = -1e30f, dt[9];
#pragma unroll
    for (int tp = 0; tp < 9; tp++) {
        const float sum = dred[(tp * 4 + 0) * 64 + lane] + dred[(tp * 4 + 1) * 64 + lane] +
                          dred[(tp * 4 + 2) * 64 + lane] + dred[(tp * 4 + 3) * 64 + lane];
        dt[tp] = msk[tp] * (sum * SCALE);   // masked taps: logit exactly 0
        mx = fmaxf(mx, dt[tp]);
    }
    float se = 0.f, w9[9];
#pragma unroll
    for (int tp = 0; tp < 9; tp++) { w9[tp] = __expf(dt[tp] - mx); se += w9[tp]; }
    const float inv = 1.f / se;
#pragma unroll
    for (int tp = 0; tp < 9; tp++) w9[tp] *= inv * msk[tp];  // masked v -> 0

    // V phase: same pair-read pattern.
    __align__(16) unsigned short ov[16];
#pragma unroll 4
    for (int j = 0; j < 8; j++) {
        const int rb = rb0 + w * 8 + j;
        float olo = 0.f, ohi = 0.f;
#pragma unroll
        for (int tp = 0; tp < 9; tp++) {
            const unsigned int c = Vl[rb + off33[tp]];
            olo += w9[tp] * blo(c);
            ohi += w9[tp] * bhi(c);
        }
        ov[2 * j]     = f2bf(olo);
        ov[2 * j + 1] = f2bf(ohi);
    }
    unsigned short* dst = aoT + (((size_t)(b * 49 + sblk)) * 16 + (h * 2 + (w >> 1))) * 2048
                        + lane * 32 + (w & 1) * 16;
    *reinterpret_cast<uint4*>(dst)     = *reinterpret_cast<const uint4*>(ov);
    *reinterpret_cast<uint4*>(dst + 8) = *reinterpret_cast<const uint4*>(ov + 8);
}

// ---------------------------------------------------------------------------
// GEMM3: 128o x 128s tile, BK=32, identity staging from blocked aoT/wT3,
// 16 MFMA/wave/step. grid (25, 3, 4). s-tail guarded.
// ---------------------------------------------------------------------------
__global__ __launch_bounds__(256) void gemm3(
    const unsigned short* __restrict__ aoT,  // [4][49][16][64][32]
    const unsigned short* __restrict__ wT3,  // [3][16][128][32]
    const float* __restrict__ bias,          // (384)
    float* __restrict__ out)                 // (4,384,3136) f32
{
    __shared__ __align__(16) unsigned short A_lds[128 * 32];
    __shared__ __align__(16) unsigned short B_lds[128 * 32];

    const int sblk = blockIdx.x;             // 0..24 (128-s tiles)
    const int oblk = blockIdx.y;             // 0..2
    const int b  = blockIdx.z;
    const int t  = threadIdx.x;
    const int lane = t & 63, w = t >> 6;
    const int quad = lane >> 4, mrow = lane & 15;
    const int wm = w >> 1, wn = w & 1;

    const int t0 = 2 * sblk, t1 = min(2 * sblk + 1, 48);
    const unsigned short* asrc = wT3 + (size_t)oblk * 16 * 4096;
    const unsigned short* bsrc0 = aoT + ((size_t)(b * 49 + t0)) * 16 * 2048;
    const unsigned short* bsrc1 = aoT + ((size_t)(b * 49 + t1)) * 16 * 2048;

    f32x4_t acc[4][4];
#pragma unroll
    for (int m = 0; m < 4; m++)
#pragma unroll
        for (int n = 0; n < 4; n++) acc[m][n] = (f32x4_t){0.f, 0.f, 0.f, 0.f};

    for (int kb = 0; kb < 16; kb++) {
        const uint4 a0 = *reinterpret_cast<const uint4*>(asrc + (size_t)kb * 4096 + t * 8);
        const uint4 a1 = *reinterpret_cast<const uint4*>(asrc + (size_t)kb * 4096 + 2048 + t * 8);
        const uint4 b0 = *reinterpret_cast<const uint4*>(bsrc0 + (size_t)kb * 2048 + t * 8);
        const uint4 b1 = *reinterpret_cast<const uint4*>(bsrc1 + (size_t)kb * 2048 + t * 8);

        __syncthreads();
        *reinterpret_cast<uint4*>(A_lds + t * 8) = a0;
        *reinterpret_cast<uint4*>(A_lds + 2048 + t * 8) = a1;
        *reinterpret_cast<uint4*>(B_lds + t * 8) = b0;
        *reinterpret_cast<uint4*>(B_lds + 2048 + t * 8) = b1;
        __syncthreads();

        bf16x8_t af[4], bf[4];
#pragma unroll
        for (int m = 0; m < 4; m++)
            af[m] = *reinterpret_cast<const bf16x8_t*>(&A_lds[(wm * 64 + m * 16 + mrow) * 32 + quad * 8]);
#pragma unroll
        for (int n = 0; n < 4; n++)
            bf[n] = *reinterpret_cast<const bf16x8_t*>(&B_lds[(wn * 64 + n * 16 + mrow) * 32 + quad * 8]);
#pragma unroll
        for (int m = 0; m < 4; m++)
#pragma unroll
            for (int n = 0; n < 4; n++)
                acc[m][n] = __builtin_amdgcn_mfma_f32_16x16x32_bf16(af[m], bf[n], acc[m][n], 0, 0, 0);
    }

    const int o0 = oblk * 128 + wm * 64;
    const int s0 = sblk * 128 + wn * 64;
    float* outb = out + (size_t)b * 384 * HW;
#pragma unroll
    for (int m = 0; m < 4; m++)
#pragma unroll
        for (int n = 0; n < 4; n++) {
            const int ss = s0 + n * 16 + mrow;
            if (ss < HW) {
#pragma unroll
                for (int r = 0; r < 4; r++) {
                    const int oo = o0 + m * 16 + quad * 4 + r;
                    outb[(size_t)oo * HW + ss] = acc[m][n][r] + bias[oo];
                }
            }
        }
}

extern "C" void kernel_launch(void* const* d_in, const int* in_sizes, int n_in,
                              void* d_out, int out_size, void* d_ws, size_t ws_size,
                              hipStream_t stream) {
    const float* x   = (const float*)d_in[0];
    const float* Wq  = (const float*)d_in[1];
    const float* Wkv = (const float*)d_in[2];
    const float* Wo  = (const float*)d_in[3];
    const float* bo  = (const float*)d_in[4];
    float* out = (float*)d_out;

    // ws layout (bf16 elements)
    unsigned short* xT  = (unsigned short*)d_ws;                  // 4,915,200
    unsigned short* wT  = xT + (size_t)4915200;                   //   589,824
    unsigned short* wT3 = wT + (size_t)589824;                    //   196,608
    unsigned short* qb  = wT3 + (size_t)196608;                   // 6,422,528
    unsigned short* kT  = qb + (size_t)6422528;                   // 6,422,528
    unsigned short* vT  = kT + (size_t)6422528;                   // 6,422,528
    unsigned short* aoT = vT + (size_t)6422528;                   // 6,422,528

    cvt_all<<<dim3(2784), 256, 0, stream>>>(x, Wq, Wkv, Wo, xT, wT, wT3);
    gemm1<<<dim3(25, 12, 4), 256, 0, stream>>>(xT, wT, qb, kT, vT);
    natt4<<<dim3(49, 8, 4), 256, 0, stream>>>(qb, kT, vT, aoT);
    gemm3<<<dim3(25, 3, 4), 256, 0, stream>>>(aoT, wT3, bo, out);
}